// Round 2
// baseline (1257.688 us; speedup 1.0000x reference)
//
#include <hip/hip_runtime.h>

// Double bilinear grid_sample, align_corners=False, zeros padding.
// feature: [8,64,256,256] f32; grid: [8,256,256,2] f32.
// Pass 1: ws = grid_sample(feature, grid); Pass 2: out = grid_sample(ws, grid).

#define GS_N 8
#define GS_C 64
#define GS_H 256
#define GS_W 256

__global__ __launch_bounds__(256) void gs_pass(const float* __restrict__ src,
                                               const float* __restrict__ grid,
                                               float* __restrict__ dst) {
    int t = blockIdx.x * blockDim.x + threadIdx.x;   // enumerates (n, ho, wo)
    int wo = t & (GS_W - 1);
    int ho = (t >> 8) & (GS_H - 1);
    int n  = t >> 16;

    // grid is [N,Ho,Wo,2] contiguous -> float2 index == t (coalesced 8B/lane)
    float2 g = ((const float2*)grid)[t];

    // ix = ((gx+1)*W - 1)*0.5 = gx*128 + 127.5 ; same for iy (H==W==256)
    float ix = fmaf(g.x, 128.0f, 127.5f);
    float iy = fmaf(g.y, 128.0f, 127.5f);

    float fx0 = floorf(ix), fy0 = floorf(iy);
    float fx = ix - fx0;
    float fy = iy - fy0;
    int x0 = (int)fx0, y0 = (int)fy0;
    int x1 = x0 + 1,   y1 = y0 + 1;

    float wx1 = fx, wx0 = 1.0f - fx;
    float wy1 = fy, wy0 = 1.0f - fy;

    // zero-padding: fold validity masks into the weights once
    float mx0 = (x0 >= 0 && x0 < GS_W) ? 1.0f : 0.0f;
    float mx1 = (x1 >= 0 && x1 < GS_W) ? 1.0f : 0.0f;
    float my0 = (y0 >= 0 && y0 < GS_H) ? 1.0f : 0.0f;
    float my1 = (y1 >= 0 && y1 < GS_H) ? 1.0f : 0.0f;

    float w00 = wx0 * wy0 * mx0 * my0;
    float w01 = wx1 * wy0 * mx1 * my0;
    float w10 = wx0 * wy1 * mx0 * my1;
    float w11 = wx1 * wy1 * mx1 * my1;

    // clipped coords (loads always in-bounds; masked weights kill OOB terms)
    int x0c = min(max(x0, 0), GS_W - 1);
    int x1c = min(max(x1, 0), GS_W - 1);
    int y0c = min(max(y0, 0), GS_H - 1);
    int y1c = min(max(y1, 0), GS_H - 1);

    int o00 = y0c * GS_W + x0c;
    int o01 = y0c * GS_W + x1c;
    int o10 = y1c * GS_W + x0c;
    int o11 = y1c * GS_W + x1c;

    const float* sp = src + (size_t)n * (GS_C * GS_H * GS_W);
    float*       dp = dst + (size_t)n * (GS_C * GS_H * GS_W) + ho * GS_W + wo;

    #pragma unroll 4
    for (int c = 0; c < GS_C; ++c) {
        const float* p = sp + c * (GS_H * GS_W);
        float v = p[o00] * w00 + p[o01] * w01 + p[o10] * w10 + p[o11] * w11;
        dp[c * (GS_H * GS_W)] = v;
    }
}

extern "C" void kernel_launch(void* const* d_in, const int* in_sizes, int n_in,
                              void* d_out, int out_size, void* d_ws, size_t ws_size,
                              hipStream_t stream) {
    const float* feature = (const float*)d_in[0];
    const float* grid    = (const float*)d_in[1];
    float*       out     = (float*)d_out;
    float*       ws      = (float*)d_ws;   // holds the intermediate [8,64,256,256]

    const int spatial = GS_N * GS_H * GS_W;      // 524288 threads
    dim3 block(256);
    dim3 grd(spatial / 256);                      // 2048 blocks

    gs_pass<<<grd, block, 0, stream>>>(feature, grid, ws);
    gs_pass<<<grd, block, 0, stream>>>(ws, grid, out);
}

// Round 3
// 506.935 us; speedup vs baseline: 2.4810x; 2.4810x over previous
//
#include <hip/hip_runtime.h>

// Double bilinear grid_sample (align_corners=False, zeros padding), fused.
// feature: [8,64,256,256] f32 NCHW; grid: [8,256,256,2] f32.
//
// Step 1: transpose feature NCHW -> NHWC into ws (channels contiguous).
// Step 2: fused double-sample:
//   out(p) = sum_k w_k(p) * mid(corner_k(p)),  mid at integer (y,x) uses
//   grid[n,y,x] -> 16 feature gathers per point with combined weights.
//   Wave lanes = channels -> every feature gather is one coalesced 256 B load.
//   Output staged via LDS tile so the NCHW write is coalesced over wo.

#define GS_N 8
#define GS_C 64
#define GS_H 256
#define GS_W 256
#define GS_HW (GS_H * GS_W)           // 65536
#define GS_IMG (GS_C * GS_HW)         // 4194304 floats per n

__global__ __launch_bounds__(256) void transpose_nchw_to_nhwc(
        const float* __restrict__ src, float* __restrict__ dst) {
    // block: one n, 64 consecutive hw positions, all 64 channels
    int b   = blockIdx.x;             // 8 * 1024 = 8192 blocks
    int n   = b >> 10;
    int hw0 = (b & 1023) << 6;

    __shared__ float lt[64][65];      // [c][hw_local], pad 65

    const float* sp = src + (size_t)n * GS_IMG;
    float*       dp = dst + (size_t)n * GS_IMG + ((size_t)hw0 << 6);

    int i  = threadIdx.x & 63;        // hw_local (coalesced read lanes)
    int c0 = threadIdx.x >> 6;        // 0..3
    #pragma unroll
    for (int c = c0; c < 64; c += 4)
        lt[c][i] = sp[((size_t)c << 16) + hw0 + i];

    __syncthreads();

    int c  = threadIdx.x & 63;        // channel (coalesced write lanes)
    int i0 = threadIdx.x >> 6;
    #pragma unroll
    for (int ii = i0; ii < 64; ii += 4)
        dp[((size_t)ii << 6) + c] = lt[c][ii];   // stride-65 LDS read: 2-way, free
}

__device__ __forceinline__ void corner_setup(float gx, float gy,
        int& x0, int& y0, float& w00, float& w01, float& w10, float& w11) {
    // ix = ((gx+1)*256 - 1)*0.5 = gx*128 + 127.5
    float ix = fmaf(gx, 128.0f, 127.5f);
    float iy = fmaf(gy, 128.0f, 127.5f);
    float fx0 = floorf(ix), fy0 = floorf(iy);
    float fx = ix - fx0, fy = iy - fy0;
    x0 = (int)fx0; y0 = (int)fy0;
    int x1 = x0 + 1, y1 = y0 + 1;
    float mx0 = (x0 >= 0 && x0 < GS_W) ? 1.0f : 0.0f;
    float mx1 = (x1 >= 0 && x1 < GS_W) ? 1.0f : 0.0f;
    float my0 = (y0 >= 0 && y0 < GS_H) ? 1.0f : 0.0f;
    float my1 = (y1 >= 0 && y1 < GS_H) ? 1.0f : 0.0f;
    w00 = (1.0f - fx) * (1.0f - fy) * mx0 * my0;
    w01 = fx * (1.0f - fy) * mx1 * my0;
    w10 = (1.0f - fx) * fy * mx0 * my1;
    w11 = fx * fy * mx1 * my1;
}

__global__ __launch_bounds__(256) void gs_fused(
        const float* __restrict__ fnhwc, const float* __restrict__ grid,
        float* __restrict__ out) {
    // block: 64 consecutive spatial points (one n, one ho, wo0..wo0+63)
    // 4 waves x 16 points; lanes = channels
    int b  = blockIdx.x;              // 8192 blocks
    int p0 = b << 6;                  // first global point index (n*65536+ho*256+wo0)
    int n  = p0 >> 16;

    __shared__ float tile[64][65];    // [c][point_local]

    int lane = threadIdx.x & 63;      // channel
    int wave = threadIdx.x >> 6;      // 0..3

    const float*  fb = fnhwc + (size_t)n * GS_IMG;
    const float2* g2 = (const float2*)grid + (size_t)n * GS_HW;  // per-n grid
    const float2* gp = (const float2*)grid;                      // global index

    for (int s = 0; s < 16; ++s) {
        int sl = wave * 16 + s;                    // block-local point
        int p  = __builtin_amdgcn_readfirstlane(p0 + sl);

        float2 g = gp[p];
        int ox0, oy0; float w00, w01, w10, w11;
        corner_setup(g.x, g.y, ox0, oy0, w00, w01, w10, w11);

        int ox0c = min(max(ox0, 0), GS_W - 1);
        int ox1c = min(max(ox0 + 1, 0), GS_W - 1);
        int oy0c = min(max(oy0, 0), GS_H - 1);
        int oy1c = min(max(oy0 + 1, 0), GS_H - 1);

        int   qk[4] = { oy0c * GS_W + ox0c, oy0c * GS_W + ox1c,
                        oy1c * GS_W + ox0c, oy1c * GS_W + ox1c };
        float wk[4] = { w00, w01, w10, w11 };

        float acc = 0.0f;
        #pragma unroll
        for (int k = 0; k < 4; ++k) {
            if (wk[k] != 0.0f) {                   // wave-uniform branch
                float2 gi = g2[qk[k]];             // grid at intermediate pixel
                int ix0, iy0; float u00, u01, u10, u11;
                corner_setup(gi.x, gi.y, ix0, iy0, u00, u01, u10, u11);

                int ix0c = min(max(ix0, 0), GS_W - 1);
                int ix1c = min(max(ix0 + 1, 0), GS_W - 1);
                int iy0c = min(max(iy0, 0), GS_H - 1);
                int iy1c = min(max(iy0 + 1, 0), GS_H - 1);

                int q00 = iy0c * GS_W + ix0c, q01 = iy0c * GS_W + ix1c;
                int q10 = iy1c * GS_W + ix0c, q11 = iy1c * GS_W + ix1c;

                float w = wk[k];
                // coalesced 256 B gathers: lanes = contiguous channels
                acc = fmaf(w * u00, fb[((size_t)q00 << 6) + lane], acc);
                acc = fmaf(w * u01, fb[((size_t)q01 << 6) + lane], acc);
                acc = fmaf(w * u10, fb[((size_t)q10 << 6) + lane], acc);
                acc = fmaf(w * u11, fb[((size_t)q11 << 6) + lane], acc);
            }
        }
        tile[lane][sl] = acc;
    }

    __syncthreads();

    // coalesced NCHW write: lanes = wo
    int ho  = (p0 >> 8) & 255;
    int wo0 = p0 & 255;                            // 0,64,128,192
    float* ob = out + (size_t)n * GS_IMG + (size_t)ho * GS_W + wo0;
    int w  = threadIdx.x & 63;
    int c0 = threadIdx.x >> 6;
    #pragma unroll
    for (int c = c0; c < 64; c += 4)
        ob[((size_t)c << 16) + w] = tile[c][w];
}

extern "C" void kernel_launch(void* const* d_in, const int* in_sizes, int n_in,
                              void* d_out, int out_size, void* d_ws, size_t ws_size,
                              hipStream_t stream) {
    const float* feature = (const float*)d_in[0];
    const float* grid    = (const float*)d_in[1];
    float*       out     = (float*)d_out;
    float*       fnhwc   = (float*)d_ws;          // 128 MiB NHWC copy

    dim3 block(256);
    dim3 grd(GS_N * GS_HW / 64);                  // 8192 blocks

    transpose_nchw_to_nhwc<<<grd, block, 0, stream>>>(feature, fnhwc);
    gs_fused<<<grd, block, 0, stream>>>(fnhwc, grid, out);
}

// Round 4
// 463.926 us; speedup vs baseline: 2.7110x; 1.0927x over previous
//
#include <hip/hip_runtime.h>

// Double bilinear grid_sample (align_corners=False, zeros padding), fused.
// feature: [8,64,256,256] f32 NCHW; grid: [8,256,256,2] f32.
//
// K1: transpose feature NCHW -> NHWC (float4 global, conflict-free LDS).
// K2: fused double-sample. Phase 1 (lane = point): compute the 16
//     {byte-offset, combined-weight} descriptors per output point once,
//     wave-parallel, into LDS. Phase 2 (lane = channel): 16 coalesced
//     256 B gathers + fma per point. Output staged via LDS for coalesced
//     NCHW write. blockIdx&7 = n pins each n's 16 MiB slice to one XCD L2.

#define GS_N 8
#define GS_C 64
#define GS_H 256
#define GS_W 256
#define GS_HW (GS_H * GS_W)
#define GS_IMG (GS_C * GS_HW)

__global__ __launch_bounds__(256) void transpose_nchw_to_nhwc(
        const float* __restrict__ src, float* __restrict__ dst) {
    int b   = blockIdx.x;              // 8192 blocks: 64 hw x 64 c tile
    int n   = b >> 10;
    int hw0 = (b & 1023) << 6;

    __shared__ float lt[64][65];       // [c][hw_local]; (65c+hw)%32 conflict-free

    const float* sp = src + (size_t)n * GS_IMG + hw0;
    float*       dp = dst + (size_t)n * GS_IMG + ((size_t)hw0 << 6);

    int hw4 = threadIdx.x & 15;        // float4 index along hw
    int c0  = threadIdx.x >> 4;        // 0..15
    #pragma unroll
    for (int c = c0; c < 64; c += 16) {
        float4 v = *(const float4*)(sp + ((size_t)c << 16) + (hw4 << 2));
        lt[c][hw4 * 4 + 0] = v.x;
        lt[c][hw4 * 4 + 1] = v.y;
        lt[c][hw4 * 4 + 2] = v.z;
        lt[c][hw4 * 4 + 3] = v.w;
    }
    __syncthreads();

    int c4 = threadIdx.x & 15;         // float4 index along c
    int h0 = threadIdx.x >> 4;         // 0..15
    #pragma unroll
    for (int hh = h0; hh < 64; hh += 16) {
        float4 v;
        v.x = lt[c4 * 4 + 0][hh];
        v.y = lt[c4 * 4 + 1][hh];
        v.z = lt[c4 * 4 + 2][hh];
        v.w = lt[c4 * 4 + 3][hh];
        *(float4*)(dp + ((size_t)hh << 6) + (c4 << 2)) = v;
    }
}

__device__ __forceinline__ void corner_setup(float gx, float gy,
        int& x0, int& y0, float& w00, float& w01, float& w10, float& w11) {
    // ix = ((gx+1)*256 - 1)*0.5 = gx*128 + 127.5
    float ix = fmaf(gx, 128.0f, 127.5f);
    float iy = fmaf(gy, 128.0f, 127.5f);
    float fx0 = floorf(ix), fy0 = floorf(iy);
    float fx = ix - fx0, fy = iy - fy0;
    x0 = (int)fx0; y0 = (int)fy0;
    int x1 = x0 + 1, y1 = y0 + 1;
    float mx0 = (x0 >= 0 && x0 < GS_W) ? 1.0f : 0.0f;
    float mx1 = (x1 >= 0 && x1 < GS_W) ? 1.0f : 0.0f;
    float my0 = (y0 >= 0 && y0 < GS_H) ? 1.0f : 0.0f;
    float my1 = (y1 >= 0 && y1 < GS_H) ? 1.0f : 0.0f;
    w00 = (1.0f - fx) * (1.0f - fy) * mx0 * my0;
    w01 = fx * (1.0f - fy) * mx1 * my0;
    w10 = (1.0f - fx) * fy * mx0 * my1;
    w11 = fx * fy * mx1 * my1;
}

__global__ __launch_bounds__(256) void gs_fused(
        const float* __restrict__ fnhwc, const float* __restrict__ grid,
        float* __restrict__ out) {
    int b   = blockIdx.x;              // 8192
    int n   = b & 7;                   // XCD pin: HW round-robin gives XCD = b%8
    int idx = b >> 3;                  // 0..1023
    int p0  = (n << 16) + (idx << 6);  // first point (n,ho,wo0)

    __shared__ int2  s_desc[64][17];   // [point][entry] {byte_off, f32 weight}
    __shared__ float tile[64][65];     // [c][point]

    int lane = threadIdx.x & 63;
    int wave = threadIdx.x >> 6;

    const float*  fb = fnhwc + (size_t)n * GS_IMG;
    const float2* g2 = (const float2*)grid + (size_t)n * (size_t)GS_HW;

    // ---- Phase 1: wave 0, lane = point. Build 16 descriptors per point.
    if (threadIdx.x < 64) {
        int l = threadIdx.x;
        float2 g = ((const float2*)grid)[p0 + l];   // coalesced 512 B
        int ox0, oy0; float w00, w01, w10, w11;
        corner_setup(g.x, g.y, ox0, oy0, w00, w01, w10, w11);
        int x0c = min(max(ox0, 0), GS_W - 1), x1c = min(max(ox0 + 1, 0), GS_W - 1);
        int y0c = min(max(oy0, 0), GS_H - 1), y1c = min(max(oy0 + 1, 0), GS_H - 1);
        int   qk[4] = { y0c * GS_W + x0c, y0c * GS_W + x1c,
                        y1c * GS_W + x0c, y1c * GS_W + x1c };
        float wk[4] = { w00, w01, w10, w11 };
        #pragma unroll
        for (int k = 0; k < 4; ++k) {
            float2 gi = g2[qk[k]];                  // 8 B gather, L2-resident (512 KB/n)
            int ix0, iy0; float u00, u01, u10, u11;
            corner_setup(gi.x, gi.y, ix0, iy0, u00, u01, u10, u11);
            int a0 = min(max(ix0, 0), GS_W - 1), a1 = min(max(ix0 + 1, 0), GS_W - 1);
            int b0 = min(max(iy0, 0), GS_H - 1), b1 = min(max(iy0 + 1, 0), GS_H - 1);
            float w = wk[k];
            // byte offset of the 256 B channel row: pixel * 64 ch * 4 B
            s_desc[l][k * 4 + 0] = make_int2((b0 * GS_W + a0) << 8, __float_as_int(w * u00));
            s_desc[l][k * 4 + 1] = make_int2((b0 * GS_W + a1) << 8, __float_as_int(w * u01));
            s_desc[l][k * 4 + 2] = make_int2((b1 * GS_W + a0) << 8, __float_as_int(w * u10));
            s_desc[l][k * 4 + 3] = make_int2((b1 * GS_W + a1) << 8, __float_as_int(w * u11));
        }
    }
    __syncthreads();

    // ---- Phase 2: lane = channel; 16 points per wave, 16 gathers each.
    const char* fbc = (const char*)fb;
    int lane4 = lane << 2;
    #pragma unroll 1
    for (int s = 0; s < 16; ++s) {
        int sl = wave * 16 + s;
        float acc = 0.0f;
        #pragma unroll
        for (int e = 0; e < 16; ++e) {
            int2 d = s_desc[sl][e];                 // wave-uniform broadcast
            float v = *(const float*)(fbc + (size_t)(d.x + lane4));  // 256 B coalesced
            acc = fmaf(__int_as_float(d.y), v, acc);
        }
        tile[lane][sl] = acc;                       // (lane+sl)%32: 2-way, free
    }
    __syncthreads();

    // ---- coalesced NCHW write: lanes = wo
    int ho  = (p0 >> 8) & 255;
    int wo0 = p0 & 255;
    float* ob = out + (size_t)n * GS_IMG + (size_t)ho * GS_W + wo0;
    int w  = threadIdx.x & 63;
    int c0 = threadIdx.x >> 6;
    #pragma unroll
    for (int c = c0; c < 64; c += 4)
        ob[((size_t)c << 16) + w] = tile[c][w];     // wave-uniform c: conflict-free
}

extern "C" void kernel_launch(void* const* d_in, const int* in_sizes, int n_in,
                              void* d_out, int out_size, void* d_ws, size_t ws_size,
                              hipStream_t stream) {
    const float* feature = (const float*)d_in[0];
    const float* grid    = (const float*)d_in[1];
    float*       out     = (float*)d_out;
    float*       fnhwc   = (float*)d_ws;           // 128 MiB NHWC copy

    dim3 block(256);
    dim3 grd(GS_N * GS_HW / 64);                   // 8192 blocks

    transpose_nchw_to_nhwc<<<grd, block, 0, stream>>>(feature, fnhwc);
    gs_fused<<<grd, block, 0, stream>>>(fnhwc, grid, out);
}